// Round 11
// baseline (397.227 us; speedup 1.0000x reference)
//
#include <hip/hip_runtime.h>

typedef short bf16x8 __attribute__((ext_vector_type(8)));
typedef float f32x4 __attribute__((ext_vector_type(4)));
typedef float f32x2 __attribute__((ext_vector_type(2)));
typedef unsigned short u16;
typedef u16 u16x4 __attribute__((ext_vector_type(4)));

#define L_SEQ 1024
#define IDIM_ 2048
#define H_ 16
#define DK_ 128
#define DV_ 128
#define KEYD 2048
#define VALD 2048
#define CONVD 6144
#define QZD 8192          // combined qkv+z projection width
#define CH 16
#define NCH (L_SEQ / CH)

__device__ __forceinline__ u16 f2bf(float f) {
  union { float f; unsigned u; } v; v.f = f;
  unsigned r = v.u + 0x7FFF + ((v.u >> 16) & 1);  // RNE
  return (u16)(r >> 16);
}

// 16-lane allreduce, all-DPP (VALU only). Verified R3-R10.
__device__ __forceinline__ float red16(float x) {
  union U { float f; int i; } a, t;
  a.f = x;
  t.i = __builtin_amdgcn_update_dpp(0, a.i, 0xB1, 0xF, 0xF, true); a.f += t.f;
  t.i = __builtin_amdgcn_update_dpp(0, a.i, 0x4E, 0xF, 0xF, true); a.f += t.f;
  t.i = __builtin_amdgcn_update_dpp(0, a.i, 0x141, 0xF, 0xF, true); a.f += t.f;
  t.i = __builtin_amdgcn_update_dpp(0, a.i, 0x140, 0xF, 0xF, true); a.f += t.f;
  return a.f;
}

// paired-chain 8-elem partial dot (same rounding structure as R6 chains)
__device__ __forceinline__ float dot8(const f32x4 a0, const f32x4 a1,
                                      const f32x4 m0, const f32x4 m1) {
  float s0 = a0[0] * m0[0], s1 = a0[1] * m0[1];
  s0 = fmaf(a0[2], m0[2], s0); s1 = fmaf(a0[3], m0[3], s1);
  s0 = fmaf(a1[0], m1[0], s0); s1 = fmaf(a1[1], m1[1], s1);
  s0 = fmaf(a1[2], m1[2], s0); s1 = fmaf(a1[3], m1[3], s1);
  return s0 + s1;
}

__device__ __forceinline__ void gl_lds16(const float* g, float* l) {
  __builtin_amdgcn_global_load_lds(
      (const __attribute__((address_space(1))) void*)g,
      (__attribute__((address_space(3))) void*)l, 16, 0, 0);
}
__device__ __forceinline__ void gl_lds4(const float* g, float* l) {
  __builtin_amdgcn_global_load_lds(
      (const __attribute__((address_space(1))) void*)g,
      (__attribute__((address_space(3))) void*)l, 4, 0, 0);
}

// ---------------- cast x (f32 -> bf16), vectorized x4 ----------------
__global__ __launch_bounds__(256) void castx_kernel(const float* __restrict__ x,
                                                    u16* __restrict__ xb) {
  int i = (blockIdx.x * 256 + threadIdx.x) * 4;
  f32x4 v = *(const f32x4*)&x[i];
  u16x4 o = { f2bf(v[0]), f2bf(v[1]), f2bf(v[2]), f2bf(v[3]) };
  *(u16x4*)&xb[i] = o;
}

// ------------- transpose + cast: W[R][C] f32 -> WT[C][R] bf16 -------------
__global__ __launch_bounds__(256) void tcast_kernel(const float* __restrict__ W,
                                                    u16* __restrict__ WT,
                                                    int R, int C) {
  __shared__ float tile[32][33];
  int c0 = blockIdx.x * 32, r0 = blockIdx.y * 32;
  int tx = threadIdx.x & 31, ty = threadIdx.x >> 5;  // 32 x 8
#pragma unroll
  for (int j = 0; j < 4; ++j)
    tile[ty + j * 8][tx] = W[(size_t)(r0 + ty + j * 8) * C + c0 + tx];
  __syncthreads();
#pragma unroll
  for (int j = 0; j < 4; ++j)
    WT[(size_t)(c0 + ty + j * 8) * R + r0 + tx] = f2bf(tile[tx][ty + j * 8]);
}

// ---------------- NT GEMM: A[M,K] bf16, B[N,K] bf16 -> C[M,N] f32 ----------------
__global__ __launch_bounds__(256) void gemm_bt_kernel(const u16* __restrict__ A,
                                                      const u16* __restrict__ B,
                                                      float* __restrict__ C,
                                                      int M, int N, int K) {
  __shared__ short As[128 * 72];
  __shared__ short Bs[128 * 72];
  const int tid = threadIdx.x;
  const int lane = tid & 63, wave = tid >> 6;
  const int wm = wave >> 1, wn = wave & 1;
  const int m0 = blockIdx.y * 128, n0 = blockIdx.x * 128;
  const int l15 = lane & 15, lhi = lane >> 4;

  f32x4 acc[4][4] = {};

  for (int k0 = 0; k0 < K; k0 += 64) {
    __syncthreads();
#pragma unroll
    for (int i = 0; i < 4; ++i) {
      int chunk = tid + i * 256;
      int row = chunk >> 3;
      int kc = (chunk & 7) * 8;
      *(bf16x8*)&As[row * 72 + kc] =
          *(const bf16x8*)&A[(size_t)(m0 + row) * K + k0 + kc];
      *(bf16x8*)&Bs[row * 72 + kc] =
          *(const bf16x8*)&B[(size_t)(n0 + row) * K + k0 + kc];
    }
    __syncthreads();
#pragma unroll
    for (int kk = 0; kk < 64; kk += 32) {
      const int koff = kk + lhi * 8;
      bf16x8 a[4], b[4];
#pragma unroll
      for (int m = 0; m < 4; ++m)
        a[m] = *(const bf16x8*)&As[(wm * 64 + m * 16 + l15) * 72 + koff];
#pragma unroll
      for (int n = 0; n < 4; ++n)
        b[n] = *(const bf16x8*)&Bs[(wn * 64 + n * 16 + l15) * 72 + koff];
#pragma unroll
      for (int m = 0; m < 4; ++m)
#pragma unroll
        for (int n = 0; n < 4; ++n)
          acc[m][n] = __builtin_amdgcn_mfma_f32_16x16x32_bf16(a[m], b[n], acc[m][n], 0, 0, 0);
    }
  }
#pragma unroll
  for (int m = 0; m < 4; ++m)
#pragma unroll
    for (int n = 0; n < 4; ++n)
#pragma unroll
      for (int j = 0; j < 4; ++j) {
        int row = m0 + wm * 64 + m * 16 + lhi * 4 + j;
        int col = n0 + wn * 64 + n * 16 + l15;
        C[(size_t)row * N + col] = acc[m][n][j];
      }
}

// ---------------- NT GEMM, BM=64 variant (M=1024,N=2048: 256 blocks = 1/CU) ----
__global__ __launch_bounds__(256) void gemm_bt64_kernel(const u16* __restrict__ A,
                                                        const u16* __restrict__ B,
                                                        float* __restrict__ C,
                                                        int M, int N, int K) {
  __shared__ short As[64 * 72];
  __shared__ short Bs[128 * 72];
  const int tid = threadIdx.x;
  const int lane = tid & 63, wave = tid >> 6;
  const int wm = wave >> 1, wn = wave & 1;
  const int m0 = blockIdx.y * 64, n0 = blockIdx.x * 128;
  const int l15 = lane & 15, lhi = lane >> 4;

  f32x4 acc[2][4] = {};

  for (int k0 = 0; k0 < K; k0 += 64) {
    __syncthreads();
#pragma unroll
    for (int i = 0; i < 2; ++i) {
      int chunk = tid + i * 256;
      int row = chunk >> 3;
      int kc = (chunk & 7) * 8;
      *(bf16x8*)&As[row * 72 + kc] =
          *(const bf16x8*)&A[(size_t)(m0 + row) * K + k0 + kc];
    }
#pragma unroll
    for (int i = 0; i < 4; ++i) {
      int chunk = tid + i * 256;
      int row = chunk >> 3;
      int kc = (chunk & 7) * 8;
      *(bf16x8*)&Bs[row * 72 + kc] =
          *(const bf16x8*)&B[(size_t)(n0 + row) * K + k0 + kc];
    }
    __syncthreads();
#pragma unroll
    for (int kk = 0; kk < 64; kk += 32) {
      const int koff = kk + lhi * 8;
      bf16x8 a[2], b[4];
#pragma unroll
      for (int m = 0; m < 2; ++m)
        a[m] = *(const bf16x8*)&As[(wm * 32 + m * 16 + l15) * 72 + koff];
#pragma unroll
      for (int n = 0; n < 4; ++n)
        b[n] = *(const bf16x8*)&Bs[(wn * 64 + n * 16 + l15) * 72 + koff];
#pragma unroll
      for (int m = 0; m < 2; ++m)
#pragma unroll
        for (int n = 0; n < 4; ++n)
          acc[m][n] = __builtin_amdgcn_mfma_f32_16x16x32_bf16(a[m], b[n], acc[m][n], 0, 0, 0);
    }
  }
#pragma unroll
  for (int m = 0; m < 2; ++m)
#pragma unroll
    for (int n = 0; n < 4; ++n)
#pragma unroll
      for (int j = 0; j < 4; ++j) {
        int row = m0 + wm * 32 + m * 16 + lhi * 4 + j;
        int col = n0 + wn * 64 + n * 16 + l15;
        C[(size_t)row * N + col] = acc[m][n][j];
      }
}

// -------- beta/eg gates, written TRANSPOSED: egT/btT[h*1024 + l] --------
__global__ __launch_bounds__(128) void betag_kernel(const float* __restrict__ x,
                                                    const float* __restrict__ Wb,
                                                    const float* __restrict__ Wa,
                                                    const float* __restrict__ A_log,
                                                    const float* __restrict__ dt_bias,
                                                    float* __restrict__ btT,
                                                    float* __restrict__ egT) {
  int l = blockIdx.x;
  __shared__ float xs[IDIM_];
  __shared__ float redb[128], reda[128];
  for (int i = threadIdx.x; i < IDIM_; i += 128) xs[i] = x[(size_t)l * IDIM_ + i];
  __syncthreads();
  int h = threadIdx.x & 15, part = threadIdx.x >> 4;
  float sb = 0.f, sa = 0.f;
  int d0 = part * 256;
  for (int d = d0; d < d0 + 256; ++d) {
    float xv = xs[d];
    sb += xv * Wb[d * 16 + h];
    sa += xv * Wa[d * 16 + h];
  }
  redb[threadIdx.x] = sb;
  reda[threadIdx.x] = sa;
  __syncthreads();
  if (threadIdx.x < 16) {
    float b = 0.f, a = 0.f;
#pragma unroll
    for (int p = 0; p < 8; ++p) { b += redb[p * 16 + h]; a += reda[p * 16 + h]; }
    btT[h * L_SEQ + l] = 1.f / (1.f + expf(-b));
    float dtv = a + dt_bias[h];
    dtv = (dtv > 20.f) ? dtv : log1pf(expf(dtv));
    float g = -expf(A_log[h]) * dtv;
    egT[h * L_SEQ + l] = expf(g);
  }
}

// ---- fused conv+SiLU+l2norm for q,k from raw qkvz; repack [h][l][dk], qkT ----
__global__ __launch_bounds__(256) void l2qk_kernel(const float* __restrict__ qkvz,
                                                   const float* __restrict__ cw,
                                                   float* __restrict__ qn,
                                                   float* __restrict__ kn,
                                                   float* __restrict__ qkT) {
  int wid = blockIdx.x * 4 + (threadIdx.x >> 6);  // 16384 waves: l*16+h
  int lane = threadIdx.x & 63;
  int l = wid >> 4, h = wid & 15;
  const int cq = h * 128 + lane * 2;
  const int ck = KEYD + cq;
  const float* row0 = qkvz + (size_t)l * QZD;
  f32x4 wq0 = *(const f32x4*)&cw[cq * 4];
  f32x4 wq1 = *(const f32x4*)&cw[(cq + 1) * 4];
  f32x4 wk0 = *(const f32x4*)&cw[ck * 4];
  f32x4 wk1 = *(const f32x4*)&cw[(ck + 1) * 4];
  f32x2 xq = *(const f32x2*)&row0[cq];
  f32x2 xk = *(const f32x2*)&row0[ck];
  float q0 = xq[0] * wq0[3], q1 = xq[1] * wq1[3];
  float k0 = xk[0] * wk0[3], k1 = xk[1] * wk1[3];
  if (l >= 1) {
    f32x2 aq = *(const f32x2*)&row0[cq - QZD];
    f32x2 ak = *(const f32x2*)&row0[ck - QZD];
    q0 += aq[0] * wq0[2]; q1 += aq[1] * wq1[2];
    k0 += ak[0] * wk0[2]; k1 += ak[1] * wk1[2];
  }
  if (l >= 2) {
    f32x2 aq = *(const f32x2*)&row0[cq - 2 * QZD];
    f32x2 ak = *(const f32x2*)&row0[ck - 2 * QZD];
    q0 += aq[0] * wq0[1]; q1 += aq[1] * wq1[1];
    k0 += ak[0] * wk0[1]; k1 += ak[1] * wk1[1];
  }
  if (l >= 3) {
    f32x2 aq = *(const f32x2*)&row0[cq - 3 * QZD];
    f32x2 ak = *(const f32x2*)&row0[ck - 3 * QZD];
    q0 += aq[0] * wq0[0]; q1 += aq[1] * wq1[0];
    k0 += ak[0] * wk0[0]; k1 += ak[1] * wk1[0];
  }
  f32x2 qv = { q0 / (1.f + expf(-q0)), q1 / (1.f + expf(-q1)) };
  f32x2 kv = { k0 / (1.f + expf(-k0)), k1 / (1.f + expf(-k1)) };

  float ssq = qv[0] * qv[0] + qv[1] * qv[1];
  float ssk = kv[0] * kv[0] + kv[1] * kv[1];
#pragma unroll
  for (int s = 1; s < 64; s <<= 1) {
    ssq += __shfl_xor(ssq, s);
    ssk += __shfl_xor(ssk, s);
  }
  float scq = 0.08838834764831845f / sqrtf(ssq + 1e-6f);  // * DK^-0.5
  float sck = 1.f / sqrtf(ssk + 1e-6f);
  qv[0] *= scq; qv[1] *= scq;
  kv[0] *= sck; kv[1] *= sck;
  size_t base = ((size_t)h * L_SEQ + l) * 128 + lane * 2;
  *(f32x2*)&qn[base] = qv;
  *(f32x2*)&kn[base] = kv;
  float qk = qv[0] * kv[0] + qv[1] * kv[1];
#pragma unroll
  for (int s = 1; s < 64; s <<= 1) qk += __shfl_xor(qk, s);
  if (lane == 0) qkT[h * L_SEQ + l] = qk;
}

// ---- cross-step scalars: kkxT[h][l] = k_l.k_{l-1}, qkxT[h][l] = q_l.k_{l-1} ----
__global__ __launch_bounds__(256) void qx_kernel(const float* __restrict__ qn,
                                                 const float* __restrict__ kn,
                                                 float* __restrict__ kkxT,
                                                 float* __restrict__ qkxT) {
  int wid = blockIdx.x * 4 + (threadIdx.x >> 6);  // l*16+h
  int lane = threadIdx.x & 63;
  int l = wid >> 4, h = wid & 15;
  float kk = 0.f, qk = 0.f;
  if (l > 0) {
    size_t cur = ((size_t)h * L_SEQ + l) * 128 + lane * 2;
    size_t prv = cur - 128;
    f32x2 kc = *(const f32x2*)&kn[cur];
    f32x2 kp = *(const f32x2*)&kn[prv];
    f32x2 qc = *(const f32x2*)&qn[cur];
    kk = kc[0] * kp[0] + kc[1] * kp[1];
    qk = qc[0] * kp[0] + qc[1] * kp[1];
#pragma unroll
    for (int s = 1; s < 64; s <<= 1) {
      kk += __shfl_xor(kk, s);
      qk += __shfl_xor(qk, s);
    }
  }
  if (lane == 0) { kkxT[h * L_SEQ + l] = kk; qkxT[h * L_SEQ + l] = qk; }
}

// ---- fused conv+SiLU + transpose of v slice -> vT[c][l], c = h*128+dv ----
__global__ __launch_bounds__(256) void vtrans_kernel(const float* __restrict__ qkvz,
                                                     const float* __restrict__ cw,
                                                     float* __restrict__ vT) {
  __shared__ float tile[32][33];
  int c0 = blockIdx.x * 32, l0 = blockIdx.y * 32;
  int tx = threadIdx.x & 31, ty = threadIdx.x >> 5;
  const int c = 2 * KEYD + c0 + tx;
  f32x4 w = *(const f32x4*)&cw[c * 4];
#pragma unroll
  for (int j = 0; j < 4; ++j) {
    int l = l0 + ty + j * 8;
    const float* p = qkvz + (size_t)l * QZD + c;
    float s = p[0] * w[3];
    if (l >= 1) s += p[-QZD] * w[2];
    if (l >= 2) s += p[-2 * QZD] * w[1];
    if (l >= 3) s += p[-3 * QZD] * w[0];
    tile[ty + j * 8][tx] = s / (1.f + expf(-s));
  }
  __syncthreads();
#pragma unroll
  for (int j = 0; j < 4; ++j)
    vT[(size_t)(c0 + ty + j * 8) * L_SEQ + l0 + tx] = tile[tx][ty + j * 8];
}

// ---------------- sequential delta-rule scan v8: pipelined lookahead ----------
// P=16 lanes/col, 4 cols/wave, 4 waves/block, 128 blocks (R6 geometry).
// Chain-breaking identity: k_{t+1}.M_t = e_t*(k_{t+1}.M_{t-1}) + (k_{t+1}.k_t)*dl_t.
// Lookahead dots C=k_{s+1}.M, D=q_{s+1}.M run off the dl chain; skm/sqm are
// reconstructed with 2 FMAs. Chunk boundaries use direct dots after the barrier.
__global__ __launch_bounds__(256) void scan_kernel(const float* __restrict__ qn,
                                                   const float* __restrict__ kn,
                                                   const float* __restrict__ vT,
                                                   const float* __restrict__ egT,
                                                   const float* __restrict__ btT,
                                                   const float* __restrict__ qkT,
                                                   const float* __restrict__ kkxT,
                                                   const float* __restrict__ qkxT,
                                                   float* __restrict__ oatt) {
  __shared__ alignas(16) float qs[2][CH][128];
  __shared__ alignas(16) float ks[2][CH][128];
  __shared__ alignas(16) float vs[2][16][CH];
  __shared__ alignas(16) float ebc[2][5][CH];

  const int tid = threadIdx.x;
  const int wave = tid >> 6, lane = tid & 63;
  const int dk_sub = lane & 15;
  const int head = blockIdx.x & 15;
  const int dv0 = (blockIdx.x >> 4) * 16;
  const int col_local = tid >> 4;
  const int dv = dv0 + col_local;

  const float* qh = qn + (size_t)head * L_SEQ * 128;
  const float* kh = kn + (size_t)head * L_SEQ * 128;

  auto stage = [&](int chunk, int buf) {
    const int l0 = chunk * CH;
    const float* qg = qh + (size_t)l0 * 128;
    const float* kg = kh + (size_t)l0 * 128;
#pragma unroll
    for (int i = 0; i < 2; ++i) {
      int seg = i * 4 + wave;
      int off = seg * 256 + lane * 4;
      gl_lds16(qg + off, &qs[buf][0][0] + seg * 256);
      gl_lds16(kg + off, &ks[buf][0][0] + seg * 256);
    }
    {
      int idx = wave * 64 + lane;
      gl_lds4(vT + (size_t)(head * 128 + dv0 + (idx >> 4)) * L_SEQ + l0 + (idx & 15),
              &vs[buf][0][0] + wave * 64);
    }
    if (wave == 0) {  // e(0-15) b(16-31) qkT(32-47) kkx(48-63) -> ebc rows 0..3
      const float* src = (lane < 16) ? (egT + head * L_SEQ + l0 + lane)
                       : (lane < 32) ? (btT + head * L_SEQ + l0 + (lane - 16))
                       : (lane < 48) ? (qkT + head * L_SEQ + l0 + (lane - 32))
                                     : (kkxT + head * L_SEQ + l0 + (lane - 48));
      gl_lds4(src, &ebc[buf][0][0]);
    }
    if (wave == 1 && lane < 16)  // qkx -> ebc row 4
      gl_lds4(qkxT + head * L_SEQ + l0 + lane, &ebc[buf][4][0]);
  };

  stage(0, 0);
  __syncthreads();

  f32x4 Mlo = {0.f, 0.f, 0.f, 0.f}, Mhi = {0.f, 0.f, 0.f, 0.f};
  const int dkb = dk_sub * 8;
  float Cp = 0.f, Dp = 0.f, dlp = 0.f, ep = 0.f;

#pragma unroll 1
  for (int c = 0; c < NCH; ++c) {
    const int buf = c & 1;
    if (c + 1 < NCH) stage(c + 1, buf ^ 1);

    // chunk-start bulk loads: all per-step scalars for 16 steps into regs
    f32x4 ev[4], bv[4], cv[4], kxv[4], qxv[4], vv[4];
#pragma unroll
    for (int i = 0; i < 4; ++i) {
      ev[i]  = *(const f32x4*)&ebc[buf][0][i * 4];
      bv[i]  = *(const f32x4*)&ebc[buf][1][i * 4];
      cv[i]  = *(const f32x4*)&ebc[buf][2][i * 4];
      kxv[i] = *(const f32x4*)&ebc[buf][3][i * 4];
      qxv[i] = *(const f32x4*)&ebc[buf][4][i * 4];
      vv[i]  = *(const f32x4*)&vs[buf][col_local][i * 4];
    }
    // q/k ring prefetch, distance 3
    f32x4 qr[4][2], kr[4][2];
#pragma unroll
    for (int i = 0; i < 3; ++i) {
      qr[i][0] = *(const f32x4*)&qs[buf][i][dkb];
      qr[i][1] = *(const f32x4*)&qs[buf][i][dkb + 4];
      kr[i][0] = *(const f32x4*)&ks[buf][i][dkb];
      kr[i][1] = *(const f32x4*)&ks[buf][i][dkb + 4];
    }
    // chunk prologue: direct dots for s=0 against the entering state
    float skm_d = red16(dot8(kr[0][0], kr[0][1], Mlo, Mhi));
    float sqm_d = red16(dot8(qr[0][0], qr[0][1], Mlo, Mhi));

#pragma unroll
    for (int s = 0; s < CH; ++s) {
      if (s + 3 < CH) {
        qr[(s + 3) & 3][0] = *(const f32x4*)&qs[buf][s + 3][dkb];
        qr[(s + 3) & 3][1] = *(const f32x4*)&qs[buf][s + 3][dkb + 4];
        kr[(s + 3) & 3][0] = *(const f32x4*)&ks[buf][s + 3][dkb];
        kr[(s + 3) & 3][1] = *(const f32x4*)&ks[buf][s + 3][dkb + 4];
      }
      const f32x4 q0 = qr[s & 3][0], q1 = qr[s & 3][1];
      const f32x4 k0 = kr[s & 3][0], k1 = kr[s & 3][1];
      const float e = ev[s >> 2][s & 3], b = bv[s >> 2][s & 3];
      const float qk = cv[s >> 2][s & 3], v = vv[s >> 2][s & 3];

      float skm, sqm;
      if (s == 0) {
        skm = skm_d; sqm = sqm_d;
      } else {
        const float kx = kxv[s >> 2][s & 3], qx = qxv[s >> 2][s & 3];
        skm = fmaf(kx, dlp, ep * Cp);   // k_s.M_{s-1} via lookahead identity
        sqm = fmaf(qx, dlp, ep * Dp);   // q_s.M_{s-1}
      }
      float dl = (v - e * skm) * b;       // delta
      float o = fmaf(qk, dl, e * sqm);    // q.M_new
      if (dk_sub == 0)
        oatt[(size_t)((c * CH + s) * 16 + head) * 128 + dv] = o;

      // lookahead dots for step s+1, using M BEFORE this step's update
      if (s < CH - 1) {
        const f32x4 ka0 = kr[(s + 1) & 3][0], ka1 = kr[(s + 1) & 3][1];
        const f32x4 qa0 = qr[(s + 1) & 3][0], qa1 = qr[(s + 1) & 3][1];
        Cp = red16(dot8(ka0, ka1, Mlo, Mhi));
        Dp = red16(dot8(qa0, qa1, Mlo, Mhi));
      }
      // state update (after the lookahead dots read M)
#pragma unroll
      for (int i = 0; i < 4; ++i) {
        Mlo[i] = fmaf(k0[i], dl, e * Mlo[i]);
        Mhi[i] = fmaf(k1[i], dl, e * Mhi[i]);
      }
      dlp = dl; ep = e;
    }
    __syncthreads();
  }
}

// ---------------- gated RMSNorm -> bf16 (z read from qkvz cols 6144+) ----------
__global__ __launch_bounds__(256) void grms_kernel(const float* __restrict__ oatt,
                                                   const float* __restrict__ qkvz,
                                                   const float* __restrict__ norm_w,
                                                   u16* __restrict__ gn) {
  int wid = blockIdx.x * 4 + (threadIdx.x >> 6);
  int lane = threadIdx.x & 63;
  int l = wid >> 4, h = wid & 15;
  const float* o = oatt + (size_t)wid * 128;
  f32x2 ov = *(const f32x2*)&o[lane * 2];
  float ss = ov[0] * ov[0] + ov[1] * ov[1];
#pragma unroll
  for (int s = 1; s < 64; s <<= 1) ss += __shfl_xor(ss, s);
  float r = 1.f / sqrtf(ss * (1.f / 128.f) + 1e-6f);
  const float* zp = qkvz + (size_t)l * QZD + CONVD + h * 128;
  f32x2 zv = *(const f32x2*)&zp[lane * 2];
  u16 r0, r1;
  {
    float sil = zv[0] / (1.f + expf(-zv[0]));
    r0 = f2bf(ov[0] * r * norm_w[lane * 2] * sil);
    float sil1 = zv[1] / (1.f + expf(-zv[1]));
    r1 = f2bf(ov[1] * r * norm_w[lane * 2 + 1] * sil1);
  }
  u16* dst = gn + (size_t)l * VALD + h * 128 + lane * 2;
  dst[0] = r0; dst[1] = r1;
}

extern "C" void kernel_launch(void* const* d_in, const int* in_sizes, int n_in,
                              void* d_out, int out_size, void* d_ws, size_t ws_size,
                              hipStream_t stream) {
  const float* x      = (const float*)d_in[0];
  const float* Wqkv   = (const float*)d_in[1];
  const float* Wz     = (const float*)d_in[2];
  const float* Wb     = (const float*)d_in[3];
  const float* Wa     = (const float*)d_in[4];
  const float* conv_w = (const float*)d_in[5];
  const float* A_log  = (const float*)d_in[6];
  const float* dt_bias= (const float*)d_in[7];
  const float* norm_w = (const float*)d_in[8];
  const float* Wout   = (const float*)d_in[9];
  float* out = (float*)d_out;

  char* ws = (char*)d_ws;
  size_t off = 0;
  auto alloc = [&](size_t bytes) {
    void* p = ws + off;
    off = (off + bytes + 255) & ~(size_t)255;
    return p;
  };
  u16* xb     = (u16*)alloc((size_t)L_SEQ * IDIM_ * 2);
  u16* WcatT  = (u16*)alloc((size_t)QZD * IDIM_ * 2);    // rows 0..6143 Wqkv^T, 6144.. Wz^T
  u16* WoutT  = (u16*)alloc((size_t)IDIM_ * VALD * 2);
  float* qkvz = (float*)alloc((size_t)L_SEQ * QZD * 4);  // combined qkv+z projection
  float* qn   = (float*)alloc((size_t)H_ * L_SEQ * 128 * 4);
  float* kn   = (float*)alloc((size_t)H_ * L_SEQ * 128 * 4);
  float* vT   = (float*)alloc((size_t)H_ * 128 * L_SEQ * 4);
  float* btT  = (float*)alloc((size_t)L_SEQ * H_ * 4);
  float* egT  = (float*)alloc((size_t)L_SEQ * H_ * 4);
  float* qkTb = (float*)alloc((size_t)L_SEQ * H_ * 4);
  float* kkxT = (float*)alloc((size_t)L_SEQ * H_ * 4);
  float* qkxT = (float*)alloc((size_t)L_SEQ * H_ * 4);
  float* oatt = (float*)alloc((size_t)L_SEQ * H_ * DV_ * 4);
  u16* gn     = (u16*)alloc((size_t)L_SEQ * VALD * 2);

  // casts / transposes
  castx_kernel<<<(L_SEQ * IDIM_) / 1024, 256, 0, stream>>>(x, xb);
  tcast_kernel<<<dim3(CONVD / 32, IDIM_ / 32), 256, 0, stream>>>(Wqkv, WcatT, IDIM_, CONVD);
  tcast_kernel<<<dim3(VALD / 32, IDIM_ / 32), 256, 0, stream>>>(Wz, WcatT + (size_t)CONVD * IDIM_, IDIM_, VALD);
  tcast_kernel<<<dim3(IDIM_ / 32, VALD / 32), 256, 0, stream>>>(Wout, WoutT, VALD, IDIM_);

  // combined projection: [qkv | z] in one GEMM (512 blocks = 2/CU exact)
  gemm_bt_kernel<<<dim3(QZD / 128, L_SEQ / 128), 256, 0, stream>>>(xb, WcatT, qkvz, L_SEQ, QZD, IDIM_);

  // gates
  betag_kernel<<<L_SEQ, 128, 0, stream>>>(x, Wb, Wa, A_log, dt_bias, btT, egT);

  // fused conv+silu+l2norm+qk repack; cross-step scalars; fused conv+silu+v transpose
  l2qk_kernel<<<(L_SEQ * H_) / 4, 256, 0, stream>>>(qkvz, conv_w, qn, kn, qkTb);
  qx_kernel<<<(L_SEQ * H_) / 4, 256, 0, stream>>>(qn, kn, kkxT, qkxT);
  vtrans_kernel<<<dim3(VALD / 32, L_SEQ / 32), 256, 0, stream>>>(qkvz, conv_w, vT);

  // sequential scan (128 blocks, 512 waves; pipelined lookahead)
  scan_kernel<<<H_ * (DV_ / 16), 256, 0, stream>>>(qn, kn, vT, egT, btT, qkTb, kkxT, qkxT, oatt);

  // gated rmsnorm + final projection (BM=64 -> 256 blocks = 1/CU)
  grms_kernel<<<(L_SEQ * H_) / 4, 256, 0, stream>>>(oatt, qkvz, norm_w, gn);
  gemm_bt64_kernel<<<dim3(IDIM_ / 128, L_SEQ / 64), 256, 0, stream>>>(gn, WoutT, out, L_SEQ, IDIM_, VALD);
}

// Round 12
// 388.963 us; speedup vs baseline: 1.0212x; 1.0212x over previous
//
#include <hip/hip_runtime.h>

typedef short bf16x8 __attribute__((ext_vector_type(8)));
typedef float f32x4 __attribute__((ext_vector_type(4)));
typedef float f32x2 __attribute__((ext_vector_type(2)));
typedef unsigned short u16;
typedef u16 u16x4 __attribute__((ext_vector_type(4)));

#define L_SEQ 1024
#define IDIM_ 2048
#define H_ 16
#define DK_ 128
#define DV_ 128
#define KEYD 2048
#define VALD 2048
#define CONVD 6144
#define QZD 8192          // combined qkv+z projection width
#define CH 16
#define NCH (L_SEQ / CH)

__device__ __forceinline__ u16 f2bf(float f) {
  union { float f; unsigned u; } v; v.f = f;
  unsigned r = v.u + 0x7FFF + ((v.u >> 16) & 1);  // RNE
  return (u16)(r >> 16);
}

// 16-lane allreduce, all-DPP (VALU only). Verified R3-R11.
__device__ __forceinline__ float red16(float x) {
  union U { float f; int i; } a, t;
  a.f = x;
  t.i = __builtin_amdgcn_update_dpp(0, a.i, 0xB1, 0xF, 0xF, true); a.f += t.f;
  t.i = __builtin_amdgcn_update_dpp(0, a.i, 0x4E, 0xF, 0xF, true); a.f += t.f;
  t.i = __builtin_amdgcn_update_dpp(0, a.i, 0x141, 0xF, 0xF, true); a.f += t.f;
  t.i = __builtin_amdgcn_update_dpp(0, a.i, 0x140, 0xF, 0xF, true); a.f += t.f;
  return a.f;
}

__device__ __forceinline__ void gl_lds16(const float* g, float* l) {
  __builtin_amdgcn_global_load_lds(
      (const __attribute__((address_space(1))) void*)g,
      (__attribute__((address_space(3))) void*)l, 16, 0, 0);
}
__device__ __forceinline__ void gl_lds4(const float* g, float* l) {
  __builtin_amdgcn_global_load_lds(
      (const __attribute__((address_space(1))) void*)g,
      (__attribute__((address_space(3))) void*)l, 4, 0, 0);
}

// ---------------- cast x (f32 -> bf16), vectorized x4 ----------------
__global__ __launch_bounds__(256) void castx_kernel(const float* __restrict__ x,
                                                    u16* __restrict__ xb) {
  int i = (blockIdx.x * 256 + threadIdx.x) * 4;
  f32x4 v = *(const f32x4*)&x[i];
  u16x4 o = { f2bf(v[0]), f2bf(v[1]), f2bf(v[2]), f2bf(v[3]) };
  *(u16x4*)&xb[i] = o;
}

// ------------- transpose + cast: W[R][C] f32 -> WT[C][R] bf16 -------------
__global__ __launch_bounds__(256) void tcast_kernel(const float* __restrict__ W,
                                                    u16* __restrict__ WT,
                                                    int R, int C) {
  __shared__ float tile[32][33];
  int c0 = blockIdx.x * 32, r0 = blockIdx.y * 32;
  int tx = threadIdx.x & 31, ty = threadIdx.x >> 5;  // 32 x 8
#pragma unroll
  for (int j = 0; j < 4; ++j)
    tile[ty + j * 8][tx] = W[(size_t)(r0 + ty + j * 8) * C + c0 + tx];
  __syncthreads();
#pragma unroll
  for (int j = 0; j < 4; ++j)
    WT[(size_t)(c0 + ty + j * 8) * R + r0 + tx] = f2bf(tile[tx][ty + j * 8]);
}

// ---------------- NT GEMM: A[M,K] bf16, B[N,K] bf16 -> C[M,N] f32 ----------------
__global__ __launch_bounds__(256) void gemm_bt_kernel(const u16* __restrict__ A,
                                                      const u16* __restrict__ B,
                                                      float* __restrict__ C,
                                                      int M, int N, int K) {
  __shared__ short As[128 * 72];
  __shared__ short Bs[128 * 72];
  const int tid = threadIdx.x;
  const int lane = tid & 63, wave = tid >> 6;
  const int wm = wave >> 1, wn = wave & 1;
  const int m0 = blockIdx.y * 128, n0 = blockIdx.x * 128;
  const int l15 = lane & 15, lhi = lane >> 4;

  f32x4 acc[4][4] = {};

  for (int k0 = 0; k0 < K; k0 += 64) {
    __syncthreads();
#pragma unroll
    for (int i = 0; i < 4; ++i) {
      int chunk = tid + i * 256;
      int row = chunk >> 3;
      int kc = (chunk & 7) * 8;
      *(bf16x8*)&As[row * 72 + kc] =
          *(const bf16x8*)&A[(size_t)(m0 + row) * K + k0 + kc];
      *(bf16x8*)&Bs[row * 72 + kc] =
          *(const bf16x8*)&B[(size_t)(n0 + row) * K + k0 + kc];
    }
    __syncthreads();
#pragma unroll
    for (int kk = 0; kk < 64; kk += 32) {
      const int koff = kk + lhi * 8;
      bf16x8 a[4], b[4];
#pragma unroll
      for (int m = 0; m < 4; ++m)
        a[m] = *(const bf16x8*)&As[(wm * 64 + m * 16 + l15) * 72 + koff];
#pragma unroll
      for (int n = 0; n < 4; ++n)
        b[n] = *(const bf16x8*)&Bs[(wn * 64 + n * 16 + l15) * 72 + koff];
#pragma unroll
      for (int m = 0; m < 4; ++m)
#pragma unroll
        for (int n = 0; n < 4; ++n)
          acc[m][n] = __builtin_amdgcn_mfma_f32_16x16x32_bf16(a[m], b[n], acc[m][n], 0, 0, 0);
    }
  }
#pragma unroll
  for (int m = 0; m < 4; ++m)
#pragma unroll
    for (int n = 0; n < 4; ++n)
#pragma unroll
      for (int j = 0; j < 4; ++j) {
        int row = m0 + wm * 64 + m * 16 + lhi * 4 + j;
        int col = n0 + wn * 64 + n * 16 + l15;
        C[(size_t)row * N + col] = acc[m][n][j];
      }
}

// ---------------- NT GEMM, BM=64 variant (M=1024,N=2048: 256 blocks = 1/CU) ----
__global__ __launch_bounds__(256) void gemm_bt64_kernel(const u16* __restrict__ A,
                                                        const u16* __restrict__ B,
                                                        float* __restrict__ C,
                                                        int M, int N, int K) {
  __shared__ short As[64 * 72];
  __shared__ short Bs[128 * 72];
  const int tid = threadIdx.x;
  const int lane = tid & 63, wave = tid >> 6;
  const int wm = wave >> 1, wn = wave & 1;
  const int m0 = blockIdx.y * 64, n0 = blockIdx.x * 128;
  const int l15 = lane & 15, lhi = lane >> 4;

  f32x4 acc[2][4] = {};

  for (int k0 = 0; k0 < K; k0 += 64) {
    __syncthreads();
#pragma unroll
    for (int i = 0; i < 2; ++i) {
      int chunk = tid + i * 256;
      int row = chunk >> 3;
      int kc = (chunk & 7) * 8;
      *(bf16x8*)&As[row * 72 + kc] =
          *(const bf16x8*)&A[(size_t)(m0 + row) * K + k0 + kc];
    }
#pragma unroll
    for (int i = 0; i < 4; ++i) {
      int chunk = tid + i * 256;
      int row = chunk >> 3;
      int kc = (chunk & 7) * 8;
      *(bf16x8*)&Bs[row * 72 + kc] =
          *(const bf16x8*)&B[(size_t)(n0 + row) * K + k0 + kc];
    }
    __syncthreads();
#pragma unroll
    for (int kk = 0; kk < 64; kk += 32) {
      const int koff = kk + lhi * 8;
      bf16x8 a[2], b[4];
#pragma unroll
      for (int m = 0; m < 2; ++m)
        a[m] = *(const bf16x8*)&As[(wm * 32 + m * 16 + l15) * 72 + koff];
#pragma unroll
      for (int n = 0; n < 4; ++n)
        b[n] = *(const bf16x8*)&Bs[(wn * 64 + n * 16 + l15) * 72 + koff];
#pragma unroll
      for (int m = 0; m < 2; ++m)
#pragma unroll
        for (int n = 0; n < 4; ++n)
          acc[m][n] = __builtin_amdgcn_mfma_f32_16x16x32_bf16(a[m], b[n], acc[m][n], 0, 0, 0);
    }
  }
#pragma unroll
  for (int m = 0; m < 2; ++m)
#pragma unroll
    for (int n = 0; n < 4; ++n)
#pragma unroll
      for (int j = 0; j < 4; ++j) {
        int row = m0 + wm * 32 + m * 16 + lhi * 4 + j;
        int col = n0 + wn * 64 + n * 16 + l15;
        C[(size_t)row * N + col] = acc[m][n][j];
      }
}

// -------- beta/eg gates, written TRANSPOSED: egT/btT[h*1024 + l] --------
__global__ __launch_bounds__(128) void betag_kernel(const float* __restrict__ x,
                                                    const float* __restrict__ Wb,
                                                    const float* __restrict__ Wa,
                                                    const float* __restrict__ A_log,
                                                    const float* __restrict__ dt_bias,
                                                    float* __restrict__ btT,
                                                    float* __restrict__ egT) {
  int l = blockIdx.x;
  __shared__ float xs[IDIM_];
  __shared__ float redb[128], reda[128];
  for (int i = threadIdx.x; i < IDIM_; i += 128) xs[i] = x[(size_t)l * IDIM_ + i];
  __syncthreads();
  int h = threadIdx.x & 15, part = threadIdx.x >> 4;
  float sb = 0.f, sa = 0.f;
  int d0 = part * 256;
  for (int d = d0; d < d0 + 256; ++d) {
    float xv = xs[d];
    sb += xv * Wb[d * 16 + h];
    sa += xv * Wa[d * 16 + h];
  }
  redb[threadIdx.x] = sb;
  reda[threadIdx.x] = sa;
  __syncthreads();
  if (threadIdx.x < 16) {
    float b = 0.f, a = 0.f;
#pragma unroll
    for (int p = 0; p < 8; ++p) { b += redb[p * 16 + h]; a += reda[p * 16 + h]; }
    btT[h * L_SEQ + l] = 1.f / (1.f + expf(-b));
    float dtv = a + dt_bias[h];
    dtv = (dtv > 20.f) ? dtv : log1pf(expf(dtv));
    float g = -expf(A_log[h]) * dtv;
    egT[h * L_SEQ + l] = expf(g);
  }
}

// ---- fused conv+SiLU+l2norm for q,k from raw qkvz; repack [h][l][dk], qkT ----
__global__ __launch_bounds__(256) void l2qk_kernel(const float* __restrict__ qkvz,
                                                   const float* __restrict__ cw,
                                                   float* __restrict__ qn,
                                                   float* __restrict__ kn,
                                                   float* __restrict__ qkT) {
  int wid = blockIdx.x * 4 + (threadIdx.x >> 6);  // 16384 waves: l*16+h
  int lane = threadIdx.x & 63;
  int l = wid >> 4, h = wid & 15;
  const int cq = h * 128 + lane * 2;
  const int ck = KEYD + cq;
  const float* row0 = qkvz + (size_t)l * QZD;
  f32x4 wq0 = *(const f32x4*)&cw[cq * 4];
  f32x4 wq1 = *(const f32x4*)&cw[(cq + 1) * 4];
  f32x4 wk0 = *(const f32x4*)&cw[ck * 4];
  f32x4 wk1 = *(const f32x4*)&cw[(ck + 1) * 4];
  f32x2 xq = *(const f32x2*)&row0[cq];
  f32x2 xk = *(const f32x2*)&row0[ck];
  float q0 = xq[0] * wq0[3], q1 = xq[1] * wq1[3];
  float k0 = xk[0] * wk0[3], k1 = xk[1] * wk1[3];
  if (l >= 1) {
    f32x2 aq = *(const f32x2*)&row0[cq - QZD];
    f32x2 ak = *(const f32x2*)&row0[ck - QZD];
    q0 += aq[0] * wq0[2]; q1 += aq[1] * wq1[2];
    k0 += ak[0] * wk0[2]; k1 += ak[1] * wk1[2];
  }
  if (l >= 2) {
    f32x2 aq = *(const f32x2*)&row0[cq - 2 * QZD];
    f32x2 ak = *(const f32x2*)&row0[ck - 2 * QZD];
    q0 += aq[0] * wq0[1]; q1 += aq[1] * wq1[1];
    k0 += ak[0] * wk0[1]; k1 += ak[1] * wk1[1];
  }
  if (l >= 3) {
    f32x2 aq = *(const f32x2*)&row0[cq - 3 * QZD];
    f32x2 ak = *(const f32x2*)&row0[ck - 3 * QZD];
    q0 += aq[0] * wq0[0]; q1 += aq[1] * wq1[0];
    k0 += ak[0] * wk0[0]; k1 += ak[1] * wk1[0];
  }
  f32x2 qv = { q0 / (1.f + expf(-q0)), q1 / (1.f + expf(-q1)) };
  f32x2 kv = { k0 / (1.f + expf(-k0)), k1 / (1.f + expf(-k1)) };

  float ssq = qv[0] * qv[0] + qv[1] * qv[1];
  float ssk = kv[0] * kv[0] + kv[1] * kv[1];
#pragma unroll
  for (int s = 1; s < 64; s <<= 1) {
    ssq += __shfl_xor(ssq, s);
    ssk += __shfl_xor(ssk, s);
  }
  float scq = 0.08838834764831845f / sqrtf(ssq + 1e-6f);  // * DK^-0.5
  float sck = 1.f / sqrtf(ssk + 1e-6f);
  qv[0] *= scq; qv[1] *= scq;
  kv[0] *= sck; kv[1] *= sck;
  size_t base = ((size_t)h * L_SEQ + l) * 128 + lane * 2;
  *(f32x2*)&qn[base] = qv;
  *(f32x2*)&kn[base] = kv;
  float qk = qv[0] * kv[0] + qv[1] * kv[1];
#pragma unroll
  for (int s = 1; s < 64; s <<= 1) qk += __shfl_xor(qk, s);
  if (lane == 0) qkT[h * L_SEQ + l] = qk;
}

// ---- fused conv+SiLU + transpose of v slice -> vT[c][l], c = h*128+dv ----
__global__ __launch_bounds__(256) void vtrans_kernel(const float* __restrict__ qkvz,
                                                     const float* __restrict__ cw,
                                                     float* __restrict__ vT) {
  __shared__ float tile[32][33];
  int c0 = blockIdx.x * 32, l0 = blockIdx.y * 32;
  int tx = threadIdx.x & 31, ty = threadIdx.x >> 5;
  const int c = 2 * KEYD + c0 + tx;
  f32x4 w = *(const f32x4*)&cw[c * 4];
#pragma unroll
  for (int j = 0; j < 4; ++j) {
    int l = l0 + ty + j * 8;
    const float* p = qkvz + (size_t)l * QZD + c;
    float s = p[0] * w[3];
    if (l >= 1) s += p[-QZD] * w[2];
    if (l >= 2) s += p[-2 * QZD] * w[1];
    if (l >= 3) s += p[-3 * QZD] * w[0];
    tile[ty + j * 8][tx] = s / (1.f + expf(-s));
  }
  __syncthreads();
#pragma unroll
  for (int j = 0; j < 4; ++j)
    vT[(size_t)(c0 + ty + j * 8) * L_SEQ + l0 + tx] = tile[tx][ty + j * 8];
}

// ---------------- sequential delta-rule scan v10 ----------------
// R6-exact math. 2-wave blocks (128 thr, 8 dv-cols), 256 blocks -> 1 block/CU,
// all 16 blocks of head h on XCD h%8 (L2 locality). Per half-chunk (8 steps):
// bulk-load q/k into registers (32 ds_read_b128, static idx) + sched_barrier(0)
// so the compiler cannot sink reads next to use -> one lgkm drain per 8 steps.
__global__ __launch_bounds__(128, 1) void scan_kernel(const float* __restrict__ qn,
                                                      const float* __restrict__ kn,
                                                      const float* __restrict__ vT,
                                                      const float* __restrict__ egT,
                                                      const float* __restrict__ btT,
                                                      const float* __restrict__ qkT,
                                                      float* __restrict__ oatt) {
  __shared__ alignas(16) float qs[2][CH][128];
  __shared__ alignas(16) float ks[2][CH][128];
  __shared__ alignas(16) float vs[2][8][CH];
  __shared__ alignas(16) float ebc[2][3][CH];

  const int tid = threadIdx.x;
  const int wave = tid >> 6, lane = tid & 63;
  const int dk_sub = lane & 15;
  const int head = blockIdx.x & 15;       // all blocks of head h -> XCD h%8
  const int dv0 = (blockIdx.x >> 4) * 8;
  const int col_local = tid >> 4;         // 0..7
  const int dv = dv0 + col_local;

  const float* qh = qn + (size_t)head * L_SEQ * 128;
  const float* kh = kn + (size_t)head * L_SEQ * 128;

  auto stage = [&](int chunk, int buf) {
    const int l0 = chunk * CH;
    const float* qg = qh + (size_t)l0 * 128;
    const float* kg = kh + (size_t)l0 * 128;
#pragma unroll
    for (int i = 0; i < 4; ++i) {
      int seg = i * 2 + wave;             // 8 segments of 256 floats
      int off = seg * 256 + lane * 4;
      gl_lds16(qg + off, &qs[buf][0][0] + seg * 256);
      gl_lds16(kg + off, &ks[buf][0][0] + seg * 256);
    }
    if (wave == 1) {                      // v: 8 cols x CH = 128 floats
#pragma unroll
      for (int i = 0; i < 2; ++i) {
        int idx = i * 64 + lane;          // col = idx>>4, step = idx&15
        gl_lds4(vT + (size_t)(head * 128 + dv0 + (idx >> 4)) * L_SEQ + l0 + (idx & 15),
                &vs[buf][0][0] + i * 64);
      }
    }
    if (wave == 0 && lane < 48) {         // e (0-15), beta (16-31), qk (32-47)
      const float* src = (lane < 16) ? (egT + head * L_SEQ + l0 + lane)
                       : (lane < 32) ? (btT + head * L_SEQ + l0 + (lane - 16))
                                     : (qkT + head * L_SEQ + l0 + (lane - 32));
      gl_lds4(src, &ebc[buf][0][0]);
    }
  };

  stage(0, 0);
  __syncthreads();

  f32x4 Mlo = {0.f, 0.f, 0.f, 0.f}, Mhi = {0.f, 0.f, 0.f, 0.f};
  const int dkb = dk_sub * 8;

#pragma unroll 1
  for (int c = 0; c < NCH; ++c) {
    const int buf = c & 1;
    if (c + 1 < NCH) stage(c + 1, buf ^ 1);

    // chunk-start bulk loads: per-step scalars for 16 steps into regs
    f32x4 ev[4], bv[4], cv[4], vv[4];
#pragma unroll
    for (int i = 0; i < 4; ++i) {
      ev[i] = *(const f32x4*)&ebc[buf][0][i * 4];
      bv[i] = *(const f32x4*)&ebc[buf][1][i * 4];
      cv[i] = *(const f32x4*)&ebc[buf][2][i * 4];
      vv[i] = *(const f32x4*)&vs[buf][col_local][i * 4];
    }

#pragma unroll
    for (int hcf = 0; hcf < 2; ++hcf) {
      // bulk register load: 8 steps of q/k (static indices, 32 ds_read_b128)
      f32x4 qb0[8], qb1[8], kb0[8], kb1[8];
#pragma unroll
      for (int i = 0; i < 8; ++i) {
        qb0[i] = *(const f32x4*)&qs[buf][hcf * 8 + i][dkb];
        qb1[i] = *(const f32x4*)&qs[buf][hcf * 8 + i][dkb + 4];
        kb0[i] = *(const f32x4*)&ks[buf][hcf * 8 + i][dkb];
        kb1[i] = *(const f32x4*)&ks[buf][hcf * 8 + i][dkb + 4];
      }
      __builtin_amdgcn_sched_barrier(0);  // pin: reads stay above compute

#pragma unroll
      for (int s = 0; s < 8; ++s) {
        const int st = hcf * 8 + s;
        const f32x4 q0 = qb0[s], q1 = qb1[s];
        const f32x4 k0 = kb0[s], k1 = kb1[s];
        const float e = ev[st >> 2][st & 3], b = bv[st >> 2][st & 3];
        const float qk = cv[st >> 2][st & 3], v = vv[st >> 2][st & 3];

        // dots on M_old: two independent fma chains each (R6-exact)
        float skm0 = k0[0] * Mlo[0], skm1 = k0[1] * Mlo[1];
        float sqm0 = q0[0] * Mlo[0], sqm1 = q0[1] * Mlo[1];
        skm0 = fmaf(k0[2], Mlo[2], skm0); skm1 = fmaf(k0[3], Mlo[3], skm1);
        sqm0 = fmaf(q0[2], Mlo[2], sqm0); sqm1 = fmaf(q0[3], Mlo[3], sqm1);
        skm0 = fmaf(k1[0], Mhi[0], skm0); skm1 = fmaf(k1[1], Mhi[1], skm1);
        sqm0 = fmaf(q1[0], Mhi[0], sqm0); sqm1 = fmaf(q1[1], Mhi[1], sqm1);
        skm0 = fmaf(k1[2], Mhi[2], skm0); skm1 = fmaf(k1[3], Mhi[3], skm1);
        sqm0 = fmaf(q1[2], Mhi[2], sqm0); sqm1 = fmaf(q1[3], Mhi[3], sqm1);
        f32x4 emlo, emhi;
#pragma unroll
        for (int i = 0; i < 4; ++i) { emlo[i] = e * Mlo[i]; emhi[i] = e * Mhi[i]; }
        float skm = red16(skm0 + skm1);
        float sqm = red16(sqm0 + sqm1);
        float dl = (v - e * skm) * b;       // delta
        float o = fmaf(qk, dl, e * sqm);    // q . M_new
        if (dk_sub == 0)
          oatt[(size_t)((c * CH + st) * 16 + head) * 128 + dv] = o;
#pragma unroll
        for (int i = 0; i < 4; ++i) {
          Mlo[i] = fmaf(k0[i], dl, emlo[i]);
          Mhi[i] = fmaf(k1[i], dl, emhi[i]);
        }
      }
    }
    __syncthreads();
  }
}

// ---------------- gated RMSNorm -> bf16 (z read from qkvz cols 6144+) ----------
__global__ __launch_bounds__(256) void grms_kernel(const float* __restrict__ oatt,
                                                   const float* __restrict__ qkvz,
                                                   const float* __restrict__ norm_w,
                                                   u16* __restrict__ gn) {
  int wid = blockIdx.x * 4 + (threadIdx.x >> 6);
  int lane = threadIdx.x & 63;
  int l = wid >> 4, h = wid & 15;
  const float* o = oatt + (size_t)wid * 128;
  f32x2 ov = *(const f32x2*)&o[lane * 2];
  float ss = ov[0] * ov[0] + ov[1] * ov[1];
#pragma unroll
  for (int s = 1; s < 64; s <<= 1) ss += __shfl_xor(ss, s);
  float r = 1.f / sqrtf(ss * (1.f / 128.f) + 1e-6f);
  const float* zp = qkvz + (size_t)l * QZD + CONVD + h * 128;
  f32x2 zv = *(const f32x2*)&zp[lane * 2];
  u16 r0, r1;
  {
    float sil = zv[0] / (1.f + expf(-zv[0]));
    r0 = f2bf(ov[0] * r * norm_w[lane * 2] * sil);
    float sil1 = zv[1] / (1.f + expf(-zv[1]));
    r1 = f2bf(ov[1] * r * norm_w[lane * 2 + 1] * sil1);
  }
  u16* dst = gn + (size_t)l * VALD + h * 128 + lane * 2;
  dst[0] = r0; dst[1] = r1;
}

extern "C" void kernel_launch(void* const* d_in, const int* in_sizes, int n_in,
                              void* d_out, int out_size, void* d_ws, size_t ws_size,
                              hipStream_t stream) {
  const float* x      = (const float*)d_in[0];
  const float* Wqkv   = (const float*)d_in[1];
  const float* Wz     = (const float*)d_in[2];
  const float* Wb     = (const float*)d_in[3];
  const float* Wa     = (const float*)d_in[4];
  const float* conv_w = (const float*)d_in[5];
  const float* A_log  = (const float*)d_in[6];
  const float* dt_bias= (const float*)d_in[7];
  const float* norm_w = (const float*)d_in[8];
  const float* Wout   = (const float*)d_in[9];
  float* out = (float*)d_out;

  char* ws = (char*)d_ws;
  size_t off = 0;
  auto alloc = [&](size_t bytes) {
    void* p = ws + off;
    off = (off + bytes + 255) & ~(size_t)255;
    return p;
  };
  u16* xb     = (u16*)alloc((size_t)L_SEQ * IDIM_ * 2);
  u16* WcatT  = (u16*)alloc((size_t)QZD * IDIM_ * 2);    // rows 0..6143 Wqkv^T, 6144.. Wz^T
  u16* WoutT  = (u16*)alloc((size_t)IDIM_ * VALD * 2);
  float* qkvz = (float*)alloc((size_t)L_SEQ * QZD * 4);  // combined qkv+z projection
  float* qn   = (float*)alloc((size_t)H_ * L_SEQ * 128 * 4);
  float* kn   = (float*)alloc((size_t)H_ * L_SEQ * 128 * 4);
  float* vT   = (float*)alloc((size_t)H_ * 128 * L_SEQ * 4);
  float* btT  = (float*)alloc((size_t)L_SEQ * H_ * 4);
  float* egT  = (float*)alloc((size_t)L_SEQ * H_ * 4);
  float* qkTb = (float*)alloc((size_t)L_SEQ * H_ * 4);
  float* oatt = (float*)alloc((size_t)L_SEQ * H_ * DV_ * 4);
  u16* gn     = (u16*)alloc((size_t)L_SEQ * VALD * 2);

  // casts / transposes
  castx_kernel<<<(L_SEQ * IDIM_) / 1024, 256, 0, stream>>>(x, xb);
  tcast_kernel<<<dim3(CONVD / 32, IDIM_ / 32), 256, 0, stream>>>(Wqkv, WcatT, IDIM_, CONVD);
  tcast_kernel<<<dim3(VALD / 32, IDIM_ / 32), 256, 0, stream>>>(Wz, WcatT + (size_t)CONVD * IDIM_, IDIM_, VALD);
  tcast_kernel<<<dim3(IDIM_ / 32, VALD / 32), 256, 0, stream>>>(Wout, WoutT, VALD, IDIM_);

  // combined projection: [qkv | z] in one GEMM (512 blocks = 2/CU exact)
  gemm_bt_kernel<<<dim3(QZD / 128, L_SEQ / 128), 256, 0, stream>>>(xb, WcatT, qkvz, L_SEQ, QZD, IDIM_);

  // gates
  betag_kernel<<<L_SEQ, 128, 0, stream>>>(x, Wb, Wa, A_log, dt_bias, btT, egT);

  // fused conv+silu+l2norm+qk repack; fused conv+silu+v transpose
  l2qk_kernel<<<(L_SEQ * H_) / 4, 256, 0, stream>>>(qkvz, conv_w, qn, kn, qkTb);
  vtrans_kernel<<<dim3(VALD / 32, L_SEQ / 32), 256, 0, stream>>>(qkvz, conv_w, vT);

  // sequential scan (256 blocks x 128 thr; bulk register loads per half-chunk)
  scan_kernel<<<H_ * (DV_ / 8), 128, 0, stream>>>(qn, kn, vT, egT, btT, qkTb, oatt);

  // gated rmsnorm + final projection (BM=64 -> 256 blocks = 1/CU)
  grms_kernel<<<(L_SEQ * H_) / 4, 256, 0, stream>>>(oatt, qkvz, norm_w, gn);
  gemm_bt64_kernel<<<dim3(IDIM_ / 128, L_SEQ / 64), 256, 0, stream>>>(gn, WoutT, out, L_SEQ, IDIM_, VALD);
}

// Round 13
// 368.752 us; speedup vs baseline: 1.0772x; 1.0548x over previous
//
#include <hip/hip_runtime.h>

typedef short bf16x8 __attribute__((ext_vector_type(8)));
typedef float f32x4 __attribute__((ext_vector_type(4)));
typedef float f32x2 __attribute__((ext_vector_type(2)));
typedef unsigned short u16;
typedef u16 u16x4 __attribute__((ext_vector_type(4)));

#define L_SEQ 1024
#define IDIM_ 2048
#define H_ 16
#define DK_ 128
#define DV_ 128
#define KEYD 2048
#define VALD 2048
#define CONVD 6144
#define QZD 8192          // combined qkv+z projection width
#define CH 16
#define NCH (L_SEQ / CH)

__device__ __forceinline__ u16 f2bf(float f) {
  union { float f; unsigned u; } v; v.f = f;
  unsigned r = v.u + 0x7FFF + ((v.u >> 16) & 1);  // RNE
  return (u16)(r >> 16);
}

// 16-lane allreduce, all-DPP (VALU only). Verified R3-R12.
__device__ __forceinline__ float red16(float x) {
  union U { float f; int i; } a, t;
  a.f = x;
  t.i = __builtin_amdgcn_update_dpp(0, a.i, 0xB1, 0xF, 0xF, true); a.f += t.f;
  t.i = __builtin_amdgcn_update_dpp(0, a.i, 0x4E, 0xF, 0xF, true); a.f += t.f;
  t.i = __builtin_amdgcn_update_dpp(0, a.i, 0x141, 0xF, 0xF, true); a.f += t.f;
  t.i = __builtin_amdgcn_update_dpp(0, a.i, 0x140, 0xF, 0xF, true); a.f += t.f;
  return a.f;
}

__device__ __forceinline__ void gl_lds16(const float* g, float* l) {
  __builtin_amdgcn_global_load_lds(
      (const __attribute__((address_space(1))) void*)g,
      (__attribute__((address_space(3))) void*)l, 16, 0, 0);
}
__device__ __forceinline__ void gl_lds4(const float* g, float* l) {
  __builtin_amdgcn_global_load_lds(
      (const __attribute__((address_space(1))) void*)g,
      (__attribute__((address_space(3))) void*)l, 4, 0, 0);
}

// ---- merged cast/transpose prep: castx + tcast(Wqkv) + tcast(Wz) + tcast(Wout) ----
// grid ranges: [0,2048) castx, [2048,14336) Wqkv, [14336,18432) Wz, [18432,22528) Wout
__global__ __launch_bounds__(256) void prepcast_kernel(const float* __restrict__ x,
                                                       const float* __restrict__ Wqkv,
                                                       const float* __restrict__ Wz,
                                                       const float* __restrict__ Wout,
                                                       u16* __restrict__ xb,
                                                       u16* __restrict__ WcatT,
                                                       u16* __restrict__ WoutT) {
  __shared__ float tile[32][33];
  const int bid = blockIdx.x;
  if (bid < 2048) {                       // castx: x f32 -> bf16 x4
    int i = (bid * 256 + threadIdx.x) * 4;
    f32x4 v = *(const f32x4*)&x[i];
    u16x4 o = { f2bf(v[0]), f2bf(v[1]), f2bf(v[2]), f2bf(v[3]) };
    *(u16x4*)&xb[i] = o;
    return;
  }
  // transpose+cast paths: W[R][C] -> WT[C][R]
  const float* W; u16* WT; int R, C, bx, by;
  if (bid < 14336) {
    int t = bid - 2048;  bx = t % 192; by = t / 192;
    W = Wqkv; WT = WcatT; R = IDIM_; C = CONVD;
  } else if (bid < 18432) {
    int t = bid - 14336; bx = t & 63; by = t >> 6;
    W = Wz; WT = WcatT + (size_t)CONVD * IDIM_; R = IDIM_; C = VALD;
  } else {
    int t = bid - 18432; bx = t & 63; by = t >> 6;
    W = Wout; WT = WoutT; R = VALD; C = IDIM_;
  }
  int c0 = bx * 32, r0 = by * 32;
  int tx = threadIdx.x & 31, ty = threadIdx.x >> 5;  // 32 x 8
#pragma unroll
  for (int j = 0; j < 4; ++j)
    tile[ty + j * 8][tx] = W[(size_t)(r0 + ty + j * 8) * C + c0 + tx];
  __syncthreads();
#pragma unroll
  for (int j = 0; j < 4; ++j)
    WT[(size_t)(c0 + ty + j * 8) * R + r0 + tx] = f2bf(tile[tx][ty + j * 8]);
}

// ---------------- NT GEMM: A[M,K] bf16, B[N,K] bf16 -> C[M,N] f32 ----------------
__global__ __launch_bounds__(256) void gemm_bt_kernel(const u16* __restrict__ A,
                                                      const u16* __restrict__ B,
                                                      float* __restrict__ C,
                                                      int M, int N, int K) {
  __shared__ short As[128 * 72];
  __shared__ short Bs[128 * 72];
  const int tid = threadIdx.x;
  const int lane = tid & 63, wave = tid >> 6;
  const int wm = wave >> 1, wn = wave & 1;
  const int m0 = blockIdx.y * 128, n0 = blockIdx.x * 128;
  const int l15 = lane & 15, lhi = lane >> 4;

  f32x4 acc[4][4] = {};

  for (int k0 = 0; k0 < K; k0 += 64) {
    __syncthreads();
#pragma unroll
    for (int i = 0; i < 4; ++i) {
      int chunk = tid + i * 256;
      int row = chunk >> 3;
      int kc = (chunk & 7) * 8;
      *(bf16x8*)&As[row * 72 + kc] =
          *(const bf16x8*)&A[(size_t)(m0 + row) * K + k0 + kc];
      *(bf16x8*)&Bs[row * 72 + kc] =
          *(const bf16x8*)&B[(size_t)(n0 + row) * K + k0 + kc];
    }
    __syncthreads();
#pragma unroll
    for (int kk = 0; kk < 64; kk += 32) {
      const int koff = kk + lhi * 8;
      bf16x8 a[4], b[4];
#pragma unroll
      for (int m = 0; m < 4; ++m)
        a[m] = *(const bf16x8*)&As[(wm * 64 + m * 16 + l15) * 72 + koff];
#pragma unroll
      for (int n = 0; n < 4; ++n)
        b[n] = *(const bf16x8*)&Bs[(wn * 64 + n * 16 + l15) * 72 + koff];
#pragma unroll
      for (int m = 0; m < 4; ++m)
#pragma unroll
        for (int n = 0; n < 4; ++n)
          acc[m][n] = __builtin_amdgcn_mfma_f32_16x16x32_bf16(a[m], b[n], acc[m][n], 0, 0, 0);
    }
  }
#pragma unroll
  for (int m = 0; m < 4; ++m)
#pragma unroll
    for (int n = 0; n < 4; ++n)
#pragma unroll
      for (int j = 0; j < 4; ++j) {
        int row = m0 + wm * 64 + m * 16 + lhi * 4 + j;
        int col = n0 + wn * 64 + n * 16 + l15;
        C[(size_t)row * N + col] = acc[m][n][j];
      }
}

// ---------------- NT GEMM, BM=64 variant (M=1024,N=2048: 256 blocks = 1/CU) ----
__global__ __launch_bounds__(256) void gemm_bt64_kernel(const u16* __restrict__ A,
                                                        const u16* __restrict__ B,
                                                        float* __restrict__ C,
                                                        int M, int N, int K) {
  __shared__ short As[64 * 72];
  __shared__ short Bs[128 * 72];
  const int tid = threadIdx.x;
  const int lane = tid & 63, wave = tid >> 6;
  const int wm = wave >> 1, wn = wave & 1;
  const int m0 = blockIdx.y * 64, n0 = blockIdx.x * 128;
  const int l15 = lane & 15, lhi = lane >> 4;

  f32x4 acc[2][4] = {};

  for (int k0 = 0; k0 < K; k0 += 64) {
    __syncthreads();
#pragma unroll
    for (int i = 0; i < 2; ++i) {
      int chunk = tid + i * 256;
      int row = chunk >> 3;
      int kc = (chunk & 7) * 8;
      *(bf16x8*)&As[row * 72 + kc] =
          *(const bf16x8*)&A[(size_t)(m0 + row) * K + k0 + kc];
    }
#pragma unroll
    for (int i = 0; i < 4; ++i) {
      int chunk = tid + i * 256;
      int row = chunk >> 3;
      int kc = (chunk & 7) * 8;
      *(bf16x8*)&Bs[row * 72 + kc] =
          *(const bf16x8*)&B[(size_t)(n0 + row) * K + k0 + kc];
    }
    __syncthreads();
#pragma unroll
    for (int kk = 0; kk < 64; kk += 32) {
      const int koff = kk + lhi * 8;
      bf16x8 a[2], b[4];
#pragma unroll
      for (int m = 0; m < 2; ++m)
        a[m] = *(const bf16x8*)&As[(wm * 32 + m * 16 + l15) * 72 + koff];
#pragma unroll
      for (int n = 0; n < 4; ++n)
        b[n] = *(const bf16x8*)&Bs[(wn * 64 + n * 16 + l15) * 72 + koff];
#pragma unroll
      for (int m = 0; m < 2; ++m)
#pragma unroll
        for (int n = 0; n < 4; ++n)
          acc[m][n] = __builtin_amdgcn_mfma_f32_16x16x32_bf16(a[m], b[n], acc[m][n], 0, 0, 0);
    }
  }
#pragma unroll
  for (int m = 0; m < 2; ++m)
#pragma unroll
    for (int n = 0; n < 4; ++n)
#pragma unroll
      for (int j = 0; j < 4; ++j) {
        int row = m0 + wm * 32 + m * 16 + lhi * 4 + j;
        int col = n0 + wn * 64 + n * 16 + l15;
        C[(size_t)row * N + col] = acc[m][n][j];
      }
}

// -------- beta/eg gates, written TRANSPOSED: egT/btT[h*1024 + l] --------
__global__ __launch_bounds__(128) void betag_kernel(const float* __restrict__ x,
                                                    const float* __restrict__ Wb,
                                                    const float* __restrict__ Wa,
                                                    const float* __restrict__ A_log,
                                                    const float* __restrict__ dt_bias,
                                                    float* __restrict__ btT,
                                                    float* __restrict__ egT) {
  int l = blockIdx.x;
  __shared__ float xs[IDIM_];
  __shared__ float redb[128], reda[128];
  for (int i = threadIdx.x; i < IDIM_; i += 128) xs[i] = x[(size_t)l * IDIM_ + i];
  __syncthreads();
  int h = threadIdx.x & 15, part = threadIdx.x >> 4;
  float sb = 0.f, sa = 0.f;
  int d0 = part * 256;
  for (int d = d0; d < d0 + 256; ++d) {
    float xv = xs[d];
    sb += xv * Wb[d * 16 + h];
    sa += xv * Wa[d * 16 + h];
  }
  redb[threadIdx.x] = sb;
  reda[threadIdx.x] = sa;
  __syncthreads();
  if (threadIdx.x < 16) {
    float b = 0.f, a = 0.f;
#pragma unroll
    for (int p = 0; p < 8; ++p) { b += redb[p * 16 + h]; a += reda[p * 16 + h]; }
    btT[h * L_SEQ + l] = 1.f / (1.f + expf(-b));
    float dtv = a + dt_bias[h];
    dtv = (dtv > 20.f) ? dtv : log1pf(expf(dtv));
    float g = -expf(A_log[h]) * dtv;
    egT[h * L_SEQ + l] = expf(g);
  }
}

// ---- merged prep2: [0,4096) fused conv+SiLU+l2norm q/k repack + qkT;
//                    [4096,6144) fused conv+SiLU + v transpose ----
__global__ __launch_bounds__(256) void prep2_kernel(const float* __restrict__ qkvz,
                                                    const float* __restrict__ cw,
                                                    float* __restrict__ qn,
                                                    float* __restrict__ kn,
                                                    float* __restrict__ qkT,
                                                    float* __restrict__ vT) {
  __shared__ float tile[32][33];
  const int bid = blockIdx.x;
  if (bid < 4096) {
    int wid = bid * 4 + (threadIdx.x >> 6);  // l*16+h
    int lane = threadIdx.x & 63;
    int l = wid >> 4, h = wid & 15;
    const int cq = h * 128 + lane * 2;
    const int ck = KEYD + cq;
    const float* row0 = qkvz + (size_t)l * QZD;
    f32x4 wq0 = *(const f32x4*)&cw[cq * 4];
    f32x4 wq1 = *(const f32x4*)&cw[(cq + 1) * 4];
    f32x4 wk0 = *(const f32x4*)&cw[ck * 4];
    f32x4 wk1 = *(const f32x4*)&cw[(ck + 1) * 4];
    f32x2 xq = *(const f32x2*)&row0[cq];
    f32x2 xk = *(const f32x2*)&row0[ck];
    float q0 = xq[0] * wq0[3], q1 = xq[1] * wq1[3];
    float k0 = xk[0] * wk0[3], k1 = xk[1] * wk1[3];
    if (l >= 1) {
      f32x2 aq = *(const f32x2*)&row0[cq - QZD];
      f32x2 ak = *(const f32x2*)&row0[ck - QZD];
      q0 += aq[0] * wq0[2]; q1 += aq[1] * wq1[2];
      k0 += ak[0] * wk0[2]; k1 += ak[1] * wk1[2];
    }
    if (l >= 2) {
      f32x2 aq = *(const f32x2*)&row0[cq - 2 * QZD];
      f32x2 ak = *(const f32x2*)&row0[ck - 2 * QZD];
      q0 += aq[0] * wq0[1]; q1 += aq[1] * wq1[1];
      k0 += ak[0] * wk0[1]; k1 += ak[1] * wk1[1];
    }
    if (l >= 3) {
      f32x2 aq = *(const f32x2*)&row0[cq - 3 * QZD];
      f32x2 ak = *(const f32x2*)&row0[ck - 3 * QZD];
      q0 += aq[0] * wq0[0]; q1 += aq[1] * wq1[0];
      k0 += ak[0] * wk0[0]; k1 += ak[1] * wk1[0];
    }
    f32x2 qv = { q0 / (1.f + expf(-q0)), q1 / (1.f + expf(-q1)) };
    f32x2 kv = { k0 / (1.f + expf(-k0)), k1 / (1.f + expf(-k1)) };

    float ssq = qv[0] * qv[0] + qv[1] * qv[1];
    float ssk = kv[0] * kv[0] + kv[1] * kv[1];
#pragma unroll
    for (int s = 1; s < 64; s <<= 1) {
      ssq += __shfl_xor(ssq, s);
      ssk += __shfl_xor(ssk, s);
    }
    float scq = 0.08838834764831845f / sqrtf(ssq + 1e-6f);  // * DK^-0.5
    float sck = 1.f / sqrtf(ssk + 1e-6f);
    qv[0] *= scq; qv[1] *= scq;
    kv[0] *= sck; kv[1] *= sck;
    size_t base = ((size_t)h * L_SEQ + l) * 128 + lane * 2;
    *(f32x2*)&qn[base] = qv;
    *(f32x2*)&kn[base] = kv;
    float qk = qv[0] * kv[0] + qv[1] * kv[1];
#pragma unroll
    for (int s = 1; s < 64; s <<= 1) qk += __shfl_xor(qk, s);
    if (lane == 0) qkT[h * L_SEQ + l] = qk;
    return;
  }
  // vtrans path
  int t = bid - 4096;
  int c0 = (t & 63) * 32, l0 = (t >> 6) * 32;
  int tx = threadIdx.x & 31, ty = threadIdx.x >> 5;
  const int c = 2 * KEYD + c0 + tx;
  f32x4 w = *(const f32x4*)&cw[c * 4];
#pragma unroll
  for (int j = 0; j < 4; ++j) {
    int l = l0 + ty + j * 8;
    const float* p = qkvz + (size_t)l * QZD + c;
    float s = p[0] * w[3];
    if (l >= 1) s += p[-QZD] * w[2];
    if (l >= 2) s += p[-2 * QZD] * w[1];
    if (l >= 3) s += p[-3 * QZD] * w[0];
    tile[ty + j * 8][tx] = s / (1.f + expf(-s));
  }
  __syncthreads();
#pragma unroll
  for (int j = 0; j < 4; ++j)
    vT[(size_t)(c0 + ty + j * 8) * L_SEQ + l0 + tx] = tile[tx][ty + j * 8];
}

// ---------------- sequential delta-rule scan (R6/R10-exact, 161us known-good) ----
// P=16 lanes/col, 4 cols/wave, 4 waves/block = 16 cols (one head, 16 dv).
// grid = 128 blocks. red16 completes the column reduce. All staging via
// global_load_lds; chunk-start bulk scalar loads; q/k ring prefetch dist 3.
__global__ __launch_bounds__(256) void scan_kernel(const float* __restrict__ qn,
                                                   const float* __restrict__ kn,
                                                   const float* __restrict__ vT,
                                                   const float* __restrict__ egT,
                                                   const float* __restrict__ btT,
                                                   const float* __restrict__ qkT,
                                                   float* __restrict__ oatt) {
  __shared__ alignas(16) float qs[2][CH][128];
  __shared__ alignas(16) float ks[2][CH][128];
  __shared__ alignas(16) float vs[2][16][CH];
  __shared__ alignas(16) float ebc[2][3][CH];

  const int tid = threadIdx.x;
  const int wave = tid >> 6, lane = tid & 63;
  const int dk_sub = lane & 15;
  const int head = blockIdx.x & 15;
  const int dv0 = (blockIdx.x >> 4) * 16;
  const int col_local = tid >> 4;
  const int dv = dv0 + col_local;

  const float* qh = qn + (size_t)head * L_SEQ * 128;
  const float* kh = kn + (size_t)head * L_SEQ * 128;

  auto stage = [&](int chunk, int buf) {
    const int l0 = chunk * CH;
    const float* qg = qh + (size_t)l0 * 128;
    const float* kg = kh + (size_t)l0 * 128;
#pragma unroll
    for (int i = 0; i < 2; ++i) {
      int seg = i * 4 + wave;
      int off = seg * 256 + lane * 4;
      gl_lds16(qg + off, &qs[buf][0][0] + seg * 256);
      gl_lds16(kg + off, &ks[buf][0][0] + seg * 256);
    }
    {
      int idx = wave * 64 + lane;
      gl_lds4(vT + (size_t)(head * 128 + dv0 + (idx >> 4)) * L_SEQ + l0 + (idx & 15),
              &vs[buf][0][0] + wave * 64);
    }
    if (wave == 0 && lane < 48) {
      const float* src = (lane < 16) ? (egT + head * L_SEQ + l0 + lane)
                       : (lane < 32) ? (btT + head * L_SEQ + l0 + (lane - 16))
                                     : (qkT + head * L_SEQ + l0 + (lane - 32));
      gl_lds4(src, &ebc[buf][0][0]);
    }
  };

  stage(0, 0);
  __syncthreads();

  f32x4 Mlo = {0.f, 0.f, 0.f, 0.f}, Mhi = {0.f, 0.f, 0.f, 0.f};
  const int dkb = dk_sub * 8;

#pragma unroll 1
  for (int c = 0; c < NCH; ++c) {
    const int buf = c & 1;
    if (c + 1 < NCH) stage(c + 1, buf ^ 1);

    f32x4 ev[4], bv[4], cv[4], vv[4];
#pragma unroll
    for (int i = 0; i < 4; ++i) {
      ev[i] = *(const f32x4*)&ebc[buf][0][i * 4];
      bv[i] = *(const f32x4*)&ebc[buf][1][i * 4];
      cv[i] = *(const f32x4*)&ebc[buf][2][i * 4];
      vv[i] = *(const f32x4*)&vs[buf][col_local][i * 4];
    }
    f32x4 qr[4][2], kr[4][2];
#pragma unroll
    for (int i = 0; i < 3; ++i) {
      qr[i][0] = *(const f32x4*)&qs[buf][i][dkb];
      qr[i][1] = *(const f32x4*)&qs[buf][i][dkb + 4];
      kr[i][0] = *(const f32x4*)&ks[buf][i][dkb];
      kr[i][1] = *(const f32x4*)&ks[buf][i][dkb + 4];
    }

#pragma unroll
    for (int s = 0; s < CH; ++s) {
      if (s + 3 < CH) {
        qr[(s + 3) & 3][0] = *(const f32x4*)&qs[buf][s + 3][dkb];
        qr[(s + 3) & 3][1] = *(const f32x4*)&qs[buf][s + 3][dkb + 4];
        kr[(s + 3) & 3][0] = *(const f32x4*)&ks[buf][s + 3][dkb];
        kr[(s + 3) & 3][1] = *(const f32x4*)&ks[buf][s + 3][dkb + 4];
      }
      const f32x4 q0 = qr[s & 3][0], q1 = qr[s & 3][1];
      const f32x4 k0 = kr[s & 3][0], k1 = kr[s & 3][1];
      const float e = ev[s >> 2][s & 3], b = bv[s >> 2][s & 3];
      const float qk = cv[s >> 2][s & 3], v = vv[s >> 2][s & 3];

      float skm0 = k0[0] * Mlo[0], skm1 = k0[1] * Mlo[1];
      float sqm0 = q0[0] * Mlo[0], sqm1 = q0[1] * Mlo[1];
      skm0 = fmaf(k0[2], Mlo[2], skm0); skm1 = fmaf(k0[3], Mlo[3], skm1);
      sqm0 = fmaf(q0[2], Mlo[2], sqm0); sqm1 = fmaf(q0[3], Mlo[3], sqm1);
      skm0 = fmaf(k1[0], Mhi[0], skm0); skm1 = fmaf(k1[1], Mhi[1], skm1);
      sqm0 = fmaf(q1[0], Mhi[0], sqm0); sqm1 = fmaf(q1[1], Mhi[1], sqm1);
      skm0 = fmaf(k1[2], Mhi[2], skm0); skm1 = fmaf(k1[3], Mhi[3], skm1);
      sqm0 = fmaf(q1[2], Mhi[2], sqm0); sqm1 = fmaf(q1[3], Mhi[3], sqm1);
      f32x4 emlo, emhi;
#pragma unroll
      for (int i = 0; i < 4; ++i) { emlo[i] = e * Mlo[i]; emhi[i] = e * Mhi[i]; }
      float skm = red16(skm0 + skm1);
      float sqm = red16(sqm0 + sqm1);
      float dl = (v - e * skm) * b;
      float o = fmaf(qk, dl, e * sqm);
      if (dk_sub == 0)
        oatt[(size_t)((c * CH + s) * 16 + head) * 128 + dv] = o;
#pragma unroll
      for (int i = 0; i < 4; ++i) {
        Mlo[i] = fmaf(k0[i], dl, emlo[i]);
        Mhi[i] = fmaf(k1[i], dl, emhi[i]);
      }
    }
    __syncthreads();
  }
}

// ---------------- gated RMSNorm -> bf16 (z read from qkvz cols 6144+) ----------
__global__ __launch_bounds__(256) void grms_kernel(const float* __restrict__ oatt,
                                                   const float* __restrict__ qkvz,
                                                   const float* __restrict__ norm_w,
                                                   u16* __restrict__ gn) {
  int wid = blockIdx.x * 4 + (threadIdx.x >> 6);
  int lane = threadIdx.x & 63;
  int l = wid >> 4, h = wid & 15;
  const float* o = oatt + (size_t)wid * 128;
  f32x2 ov = *(const f32x2*)&o[lane * 2];
  float ss = ov[0] * ov[0] + ov[1] * ov[1];
#pragma unroll
  for (int s = 1; s < 64; s <<= 1) ss += __shfl_xor(ss, s);
  float r = 1.f / sqrtf(ss * (1.f / 128.f) + 1e-6f);
  const float* zp = qkvz + (size_t)l * QZD + CONVD + h * 128;
  f32x2 zv = *(const f32x2*)&zp[lane * 2];
  u16 r0, r1;
  {
    float sil = zv[0] / (1.f + expf(-zv[0]));
    r0 = f2bf(ov[0] * r * norm_w[lane * 2] * sil);
    float sil1 = zv[1] / (1.f + expf(-zv[1]));
    r1 = f2bf(ov[1] * r * norm_w[lane * 2 + 1] * sil1);
  }
  u16* dst = gn + (size_t)l * VALD + h * 128 + lane * 2;
  dst[0] = r0; dst[1] = r1;
}

extern "C" void kernel_launch(void* const* d_in, const int* in_sizes, int n_in,
                              void* d_out, int out_size, void* d_ws, size_t ws_size,
                              hipStream_t stream) {
  const float* x      = (const float*)d_in[0];
  const float* Wqkv   = (const float*)d_in[1];
  const float* Wz     = (const float*)d_in[2];
  const float* Wb     = (const float*)d_in[3];
  const float* Wa     = (const float*)d_in[4];
  const float* conv_w = (const float*)d_in[5];
  const float* A_log  = (const float*)d_in[6];
  const float* dt_bias= (const float*)d_in[7];
  const float* norm_w = (const float*)d_in[8];
  const float* Wout   = (const float*)d_in[9];
  float* out = (float*)d_out;

  char* ws = (char*)d_ws;
  size_t off = 0;
  auto alloc = [&](size_t bytes) {
    void* p = ws + off;
    off = (off + bytes + 255) & ~(size_t)255;
    return p;
  };
  u16* xb     = (u16*)alloc((size_t)L_SEQ * IDIM_ * 2);
  u16* WcatT  = (u16*)alloc((size_t)QZD * IDIM_ * 2);    // rows 0..6143 Wqkv^T, 6144.. Wz^T
  u16* WoutT  = (u16*)alloc((size_t)IDIM_ * VALD * 2);
  float* qkvz = (float*)alloc((size_t)L_SEQ * QZD * 4);  // combined qkv+z projection
  float* qn   = (float*)alloc((size_t)H_ * L_SEQ * 128 * 4);
  float* kn   = (float*)alloc((size_t)H_ * L_SEQ * 128 * 4);
  float* vT   = (float*)alloc((size_t)H_ * 128 * L_SEQ * 4);
  float* btT  = (float*)alloc((size_t)L_SEQ * H_ * 4);
  float* egT  = (float*)alloc((size_t)L_SEQ * H_ * 4);
  float* qkTb = (float*)alloc((size_t)L_SEQ * H_ * 4);
  float* oatt = (float*)alloc((size_t)L_SEQ * H_ * DV_ * 4);
  u16* gn     = (u16*)alloc((size_t)L_SEQ * VALD * 2);

  // merged casts/transposes (1 launch instead of 4)
  prepcast_kernel<<<22528, 256, 0, stream>>>(x, Wqkv, Wz, Wout, xb, WcatT, WoutT);

  // combined projection: [qkv | z] in one GEMM (512 blocks = 2/CU exact)
  gemm_bt_kernel<<<dim3(QZD / 128, L_SEQ / 128), 256, 0, stream>>>(xb, WcatT, qkvz, L_SEQ, QZD, IDIM_);

  // gates
  betag_kernel<<<L_SEQ, 128, 0, stream>>>(x, Wb, Wa, A_log, dt_bias, btT, egT);

  // merged prep2: conv+silu+l2norm+qk repack AND conv+silu+v transpose (1 launch)
  prep2_kernel<<<6144, 256, 0, stream>>>(qkvz, conv_w, qn, kn, qkTb, vT);

  // sequential scan (128 blocks, 512 waves — R6/R10-exact, known 161us)
  scan_kernel<<<H_ * (DV_ / 16), 256, 0, stream>>>(qn, kn, vT, egT, btT, qkTb, oatt);

  // gated rmsnorm + final projection (BM=64 -> 256 blocks = 1/CU)
  grms_kernel<<<(L_SEQ * H_) / 4, 256, 0, stream>>>(oatt, qkvz, norm_w, gn);
  gemm_bt64_kernel<<<dim3(IDIM_ / 128, L_SEQ / 64), 256, 0, stream>>>(gn, WoutT, out, L_SEQ, IDIM_, VALD);
}